// Round 7
// baseline (104.454 us; speedup 1.0000x reference)
//
#include <hip/hip_runtime.h>

// Problem constants (match reference)
#define BATCH  8192
#define KK     25
#define LL     25
#define BN_EPS 1e-5f
#define PREPB  128             // prep blocks (64 rows each)
#define LG     5               // l-values per eval block
#define NLG    (LL / LG)
#define VB     4               // batch elements per thread in eval
#define WS2    152             // per-l LDS half2 weight-slab stride (entries)

// Workspace layout (float offsets):
#define WS_PART   0                         // [PREPB][50] partial sums
#define WS_SCALE  6400
#define WS_SHIFT  6432
#define WS_XT     8192                      // [LL][BATCH] transposed x
#define WS_FP     (WS_XT + LL * BATCH)      // [NLG][KK][BATCH] partial outputs
#define WS_END    (WS_FP + NLG * KK * BATCH)

typedef _Float16 h2 __attribute__((ext_vector_type(2)));

static __device__ __forceinline__ h2 bcast2(float w) {
    const _Float16 h = (_Float16)w;
    h2 r; r.x = h; r.y = h; return r;
}
static __device__ __forceinline__ h2 relu2(h2 v) {
    h2 z; z.x = (_Float16)0.f; z.y = (_Float16)0.f;
    return __builtin_elementwise_max(v, z);
}

// ---------------------------------------------------------------------------
// prep: 128 blocks x 64 rows. Coalesced read of x chunk -> LDS; coalesced
// transposed write to xT (256B runs); per-column partial sum/sumsq.
// ---------------------------------------------------------------------------
__global__ __launch_bounds__(256) void prep_kernel(
    const float* __restrict__ x,
    float* __restrict__ xT,
    float* __restrict__ part)
{
    __shared__ float xs[64 * LL];           // 6.4 KB
    __shared__ float red[400];
    const int tid = threadIdx.x;
    const int b0  = blockIdx.x * 64;

    const float* src = x + (size_t)b0 * LL;
    #pragma unroll
    for (int i = 0; i < 7; ++i) {
        const int idx = i * 256 + tid;
        if (idx < 64 * LL) xs[idx] = src[idx];
    }
    __syncthreads();

    // transposed write: idx -> (l = idx/64, r = idx%64); lanes write
    // consecutive r -> 256B coalesced runs. LDS read stride 25: conflict-free.
    #pragma unroll
    for (int i = 0; i < 7; ++i) {
        const int idx = i * 256 + tid;
        if (idx < 64 * LL) {
            const int l = idx >> 6, r = idx & 63;
            xT[l * BATCH + b0 + r] = xs[r * LL + l];
        }
    }

    // partial sums: 200 threads -> (g = tid/25 of 8, l = tid%25), 8 rows each
    float s = 0.f, s2 = 0.f;
    if (tid < 200) {
        const int l = tid % LL;
        const int g = tid / LL;
        #pragma unroll
        for (int r = 0; r < 8; ++r) {
            const float v = xs[(g * 8 + r) * LL + l];
            s += v;
            s2 = fmaf(v, v, s2);
        }
        red[tid] = s; red[200 + tid] = s2;
    }
    __syncthreads();

    if (tid < 50) {
        const int c = tid;
        float t = 0.f;
        if (c < LL) {
            #pragma unroll
            for (int g = 0; g < 8; ++g) t += red[g * LL + c];
        } else {
            #pragma unroll
            for (int g = 0; g < 8; ++g) t += red[200 + g * LL + (c - LL)];
        }
        part[blockIdx.x * 50 + c] = t;
    }
}

// ---------------------------------------------------------------------------
// stats2: reduce PREPB partials -> scale/shift for xn = x*scale + shift
// ---------------------------------------------------------------------------
__global__ __launch_bounds__(64) void stats2_kernel(
    const float* __restrict__ part,
    const float* __restrict__ gamma,
    const float* __restrict__ bn_bias,
    float* __restrict__ ws)
{
    const int c = threadIdx.x;
    float t = 0.f;
    if (c < 50)
        for (int b = 0; b < PREPB; ++b)
            t += part[b * 50 + c];

    const int src = (c < LL) ? (c + LL) : c;
    const float s2 = __shfl(t, src);

    if (c < LL) {
        const float inv_b = 1.f / (float)BATCH;
        const float mean  = t * inv_b;
        const float var   = fmaf(s2, inv_b, -mean * mean);
        const float scale = rsqrtf(var + BN_EPS) * gamma[c];
        ws[WS_SCALE + c] = scale;
        ws[WS_SHIFT + c] = fmaf(-mean, scale, bn_bias[c]);
    }
}

// ---------------------------------------------------------------------------
// eval (R7): packed-fp16 VALU. Weights staged into LDS ONCE per block as
// broadcast (w,w) half2 pairs -> hot loop reads v_pk-ready operands via
// ds_read (4 consecutive pairs combine to b128). Each thread's VB=4 batch
// elems become 2 half2 lanes -> v_pk_fma_f16 halves the instruction count
// vs the fp32 floor (9.8us). xn / bias-4 / alpha accumulation stay fp32.
// scale/shift/alpha/b4 are wave-uniform global reads -> s_load.
// LDS slab per j (stride WS2=152 h2 entries):
//   [0:8) w1 [8:16) b1 [16:80) w2 [80:88) b2 [88:136) w3 [136:142) b3 [142:148) w4
// ---------------------------------------------------------------------------
__global__ __launch_bounds__(256) void eval_kernel(
    const float* __restrict__ xT,
    const float* __restrict__ W1, const float* __restrict__ b1,
    const float* __restrict__ W2, const float* __restrict__ b2,
    const float* __restrict__ W3, const float* __restrict__ b3,
    const float* __restrict__ W4, const float* __restrict__ b4,
    const float* __restrict__ alpha,
    const float* __restrict__ ws,
    float* __restrict__ fp)
{
    __shared__ h2 wl[LG * WS2];             // 760 h2 = 3.04 KB

    const int tid = threadIdx.x;
    const int k   = blockIdx.y;
    const int g   = blockIdx.z;
    const int l0  = g * LG;
    const int kl0 = k * LL + l0;
    const int b   = (blockIdx.x * 256 + tid) * VB;

    // ---- stage weights as broadcast half2 pairs (once per block) ----
    if (tid < 40) {
        const int j = tid >> 3, e = tid & 7;
        wl[j * WS2 +      e] = bcast2(W1[(kl0 + j) * 8 + e]);
        wl[j * WS2 +  8 + e] = bcast2(b1[(kl0 + j) * 8 + e]);
        wl[j * WS2 + 80 + e] = bcast2(b2[(kl0 + j) * 8 + e]);
    }
    {   // W2: 5*64 = 320
        int t = tid;
        const int j = t >> 6, e = t & 63;
        wl[j * WS2 + 16 + e] = bcast2(W2[(kl0 + j) * 64 + e]);
        t += 256;
        if (t < LG * 64) {
            const int j2 = t >> 6, e2 = t & 63;
            wl[j2 * WS2 + 16 + e2] = bcast2(W2[(kl0 + j2) * 64 + e2]);
        }
    }
    if (tid < 240) {                         // W3: 5*48
        const int j = tid / 48, e = tid % 48;
        wl[j * WS2 + 88 + e] = bcast2(W3[(kl0 + j) * 48 + e]);
    }
    if (tid < 30) {                          // b3, w4: 5*6 each
        const int j = tid / 6, e = tid % 6;
        wl[j * WS2 + 136 + e] = bcast2(b3[(kl0 + j) * 6 + e]);
        wl[j * WS2 + 142 + e] = bcast2(W4[(kl0 + j) * 6 + e]);
    }
    __syncthreads();

    float acc[VB] = {0.f, 0.f, 0.f, 0.f};

    #pragma unroll
    for (int j = 0; j < LG; ++j) {
        const int l = l0 + j;
        const h2* w = wl + j * WS2;

        // wave-uniform scalars -> s_load
        const float scale = ws[WS_SCALE + l];
        const float shift = ws[WS_SHIFT + l];
        const float a     = alpha[l * KK + k];
        const float b4f   = b4[kl0 + j];

        const float4 xv = *(const float4*)&xT[l * BATCH + b];
        h2 xn2[2];
        {
            const float n0 = fmaf(xv.x, scale, shift);
            const float n1 = fmaf(xv.y, scale, shift);
            const float n2 = fmaf(xv.z, scale, shift);
            const float n3 = fmaf(xv.w, scale, shift);
            xn2[0].x = (_Float16)n0; xn2[0].y = (_Float16)n1;
            xn2[1].x = (_Float16)n2; xn2[1].y = (_Float16)n3;
        }

        // layer 1: 1 -> 8
        h2 hh1[2][8];
        #pragma unroll
        for (int h = 0; h < 8; ++h) {
            const h2 ww = w[h], bb = w[8 + h];
            #pragma unroll
            for (int p = 0; p < 2; ++p)
                hh1[p][h] = relu2(xn2[p] * ww + bb);
        }

        // layer 2: 8 -> 8
        h2 hh2[2][8];
        #pragma unroll
        for (int i = 0; i < 8; ++i) {
            const h2 bb = w[80 + i];
            h2 t0 = bb, t1 = bb;
            #pragma unroll
            for (int h = 0; h < 8; ++h) {
                const h2 ww = w[16 + i * 8 + h];
                t0 = hh1[0][h] * ww + t0;
                t1 = hh1[1][h] * ww + t1;
            }
            hh2[0][i] = relu2(t0);
            hh2[1][i] = relu2(t1);
        }

        // layer 3: 8 -> 6
        h2 hh3[2][6];
        #pragma unroll
        for (int jj = 0; jj < 6; ++jj) {
            const h2 bb = w[136 + jj];
            h2 t0 = bb, t1 = bb;
            #pragma unroll
            for (int i = 0; i < 8; ++i) {
                const h2 ww = w[88 + jj * 8 + i];
                t0 = hh2[0][i] * ww + t0;
                t1 = hh2[1][i] * ww + t1;
            }
            hh3[0][jj] = relu2(t0);
            hh3[1][jj] = relu2(t1);
        }

        // layer 4: 6 -> 1 (packed dot), finish in fp32
        h2 fd0, fd1;
        fd0.x = (_Float16)0.f; fd0.y = (_Float16)0.f;
        fd1 = fd0;
        #pragma unroll
        for (int jj = 0; jj < 6; ++jj) {
            const h2 ww = w[142 + jj];
            fd0 = hh3[0][jj] * ww + fd0;
            fd1 = hh3[1][jj] * ww + fd1;
        }
        acc[0] = fmaf(a, b4f + (float)fd0.x, acc[0]);
        acc[1] = fmaf(a, b4f + (float)fd0.y, acc[1]);
        acc[2] = fmaf(a, b4f + (float)fd1.x, acc[2]);
        acc[3] = fmaf(a, b4f + (float)fd1.y, acc[3]);
    }

    float4 o = {acc[0], acc[1], acc[2], acc[3]};
    *(float4*)&fp[(g * KK + k) * BATCH + b] = o;
}

// ---------------------------------------------------------------------------
// reduce: out[b][k] = beta[k] + sum_g fp[g][k][b]; coalesced loads.
// ---------------------------------------------------------------------------
__global__ __launch_bounds__(256) void reduce_kernel(
    const float* __restrict__ fp,
    const float* __restrict__ beta,
    float* __restrict__ out)
{
    const int tid = threadIdx.x;
    const int k   = blockIdx.y;
    const int b   = blockIdx.x * 256 + tid;

    float acc = beta[k];
    #pragma unroll
    for (int g = 0; g < NLG; ++g)
        acc += fp[(g * KK + k) * BATCH + b];
    out[(size_t)b * KK + k] = acc;
}

// ---------------------------------------------------------------------------
// fallbacks (small workspace) — fp32, proven correct.
// ---------------------------------------------------------------------------
__device__ __forceinline__ float mlp_eval(
    float xn, int kl,
    const float* __restrict__ W1, const float* __restrict__ b1,
    const float* __restrict__ W2, const float* __restrict__ b2,
    const float* __restrict__ W3, const float* __restrict__ b3,
    const float* __restrict__ W4, const float* __restrict__ b4)
{
    const float* w1  = W1 + kl * 8;
    const float* bb1 = b1 + kl * 8;
    float h1[8];
    #pragma unroll
    for (int h = 0; h < 8; ++h)
        h1[h] = fmaxf(fmaf(xn, w1[h], bb1[h]), 0.f);

    const float* w2  = W2 + kl * 64;
    const float* bb2 = b2 + kl * 8;
    float h2v[8];
    #pragma unroll
    for (int i = 0; i < 8; ++i) {
        float t = bb2[i];
        #pragma unroll
        for (int h = 0; h < 8; ++h)
            t = fmaf(h1[h], w2[i * 8 + h], t);
        h2v[i] = fmaxf(t, 0.f);
    }

    const float* w3  = W3 + kl * 48;
    const float* bb3 = b3 + kl * 6;
    float h3[6];
    #pragma unroll
    for (int j = 0; j < 6; ++j) {
        float t = bb3[j];
        #pragma unroll
        for (int i = 0; i < 8; ++i)
            t = fmaf(h2v[i], w3[j * 8 + i], t);
        h3[j] = fmaxf(t, 0.f);
    }

    const float* w4 = W4 + kl * 6;
    float f = b4[kl];
    #pragma unroll
    for (int j = 0; j < 6; ++j)
        f = fmaf(h3[j], w4[j], f);
    return f;
}

__global__ __launch_bounds__(256) void stats_small_kernel(
    const float* __restrict__ x,
    const float* __restrict__ gamma,
    const float* __restrict__ bn_bias,
    float* __restrict__ ws)
{
    const int l   = blockIdx.x;
    const int tid = threadIdx.x;

    float s = 0.f, s2 = 0.f;
    for (int b = tid; b < BATCH; b += 256) {
        float v = x[b * LL + l];
        s  += v;
        s2  = fmaf(v, v, s2);
    }
    for (int off = 32; off > 0; off >>= 1) {
        s  += __shfl_down(s,  off);
        s2 += __shfl_down(s2, off);
    }
    __shared__ float red[8];
    const int wave = tid >> 6;
    if ((tid & 63) == 0) { red[wave] = s; red[4 + wave] = s2; }
    __syncthreads();
    if (tid == 0) {
        s  = red[0] + red[1] + red[2] + red[3];
        s2 = red[4] + red[5] + red[6] + red[7];
        const float inv_b = 1.f / (float)BATCH;
        float mean = s * inv_b;
        float var  = fmaf(s2, inv_b, -mean * mean);
        float scale = rsqrtf(var + BN_EPS) * gamma[l];
        ws[WS_SCALE + l] = scale;
        ws[WS_SHIFT + l] = fmaf(-mean, scale, bn_bias[l]);
    }
}

__global__ __launch_bounds__(256) void mlp_lds_direct_kernel(
    const float* __restrict__ x,
    const float* __restrict__ W1, const float* __restrict__ b1,
    const float* __restrict__ W2, const float* __restrict__ b2,
    const float* __restrict__ W3, const float* __restrict__ b3,
    const float* __restrict__ W4, const float* __restrict__ b4,
    const float* __restrict__ alpha, const float* __restrict__ beta,
    const float* __restrict__ ws,
    float* __restrict__ out)
{
    __shared__ float xs[256 * LL];
    const int tid = threadIdx.x;
    const int k   = blockIdx.y;
    const int b0  = blockIdx.x * 256;

    const float* xsrc = x + (size_t)b0 * LL;
    #pragma unroll
    for (int i = 0; i < LL; ++i)
        xs[i * 256 + tid] = xsrc[i * 256 + tid];
    __syncthreads();

    float acc = beta[k];
    for (int l = 0; l < LL; ++l) {
        const int kl = k * LL + l;
        const float xn = fmaf(xs[tid * LL + l], ws[WS_SCALE + l], ws[WS_SHIFT + l]);
        const float f  = mlp_eval(xn, kl, W1, b1, W2, b2, W3, b3, W4, b4);
        acc = fmaf(alpha[l * KK + k], f, acc);
    }
    out[(size_t)(b0 + tid) * KK + k] = acc;
}

extern "C" void kernel_launch(void* const* d_in, const int* in_sizes, int n_in,
                              void* d_out, int out_size, void* d_ws, size_t ws_size,
                              hipStream_t stream) {
    const float* x       = (const float*)d_in[0];
    const float* gamma   = (const float*)d_in[1];
    const float* bn_bias = (const float*)d_in[2];
    const float* W1      = (const float*)d_in[3];
    const float* b1      = (const float*)d_in[4];
    const float* W2      = (const float*)d_in[5];
    const float* b2      = (const float*)d_in[6];
    const float* W3      = (const float*)d_in[7];
    const float* b3      = (const float*)d_in[8];
    const float* W4      = (const float*)d_in[9];
    const float* b4      = (const float*)d_in[10];
    const float* alpha   = (const float*)d_in[11];
    const float* beta    = (const float*)d_in[12];

    float* out = (float*)d_out;
    float* ws  = (float*)d_ws;
    float* xT  = ws + WS_XT;
    float* fp  = ws + WS_FP;

    const bool fast = ws_size >= (size_t)WS_END * sizeof(float);

    if (fast) {
        prep_kernel<<<dim3(PREPB), dim3(256), 0, stream>>>(x, xT, ws + WS_PART);
        stats2_kernel<<<dim3(1), dim3(64), 0, stream>>>(ws + WS_PART, gamma, bn_bias, ws);
        eval_kernel<<<dim3(BATCH / (256 * VB), KK, NLG), dim3(256), 0, stream>>>(
            xT, W1, b1, W2, b2, W3, b3, W4, b4, alpha, ws, fp);
        reduce_kernel<<<dim3(BATCH / 256, KK), dim3(256), 0, stream>>>(fp, beta, out);
    } else {
        stats_small_kernel<<<dim3(LL), dim3(256), 0, stream>>>(x, gamma, bn_bias, ws);
        mlp_lds_direct_kernel<<<dim3(BATCH / 256, KK), dim3(256), 0, stream>>>(
            x, W1, b1, W2, b2, W3, b3, W4, b4, alpha, beta, ws, out);
    }
}

// Round 9
// 102.193 us; speedup vs baseline: 1.0221x; 1.0221x over previous
//
#include <hip/hip_runtime.h>

// Problem constants (match reference)
#define BATCH  8192
#define KK     25
#define LL     25
#define BN_EPS 1e-5f
#define PREPB  32              // prep blocks (256 rows each) — R6 proven
#define LG     5               // l-values per eval block
#define NLG    (LL / LG)
#define VB     4               // batch elements per thread in eval
#define WS2    152             // per-l LDS half2 weight-slab stride (entries)

// Workspace layout (float offsets):
#define WS_PART   0                         // [PREPB][50] partial sums
#define WS_SCALE  1600                      // (fallback path only)
#define WS_SHIFT  1632
#define WS_XT     2048                      // [LL][BATCH] transposed x
#define WS_FP     (WS_XT + LL * BATCH)      // [NLG][KK][BATCH] partial outputs
#define WS_END    (WS_FP + NLG * KK * BATCH)

// Packed fp16 pair in one VGPR; asm wrappers guarantee v_pk_* selection
// (ROCm 7.2 lacks __hmax2; R7's ext_vector arithmetic may scalarize).
typedef _Float16 h2v __attribute__((ext_vector_type(2)));

static __device__ __forceinline__ h2v pk_fma(h2v a, h2v b, h2v c) {
    h2v d;
    asm("v_pk_fma_f16 %0, %1, %2, %3" : "=v"(d) : "v"(a), "v"(b), "v"(c));
    return d;
}
static __device__ __forceinline__ h2v pk_max(h2v a, h2v b) {
    h2v d;
    asm("v_pk_max_f16 %0, %1, %2" : "=v"(d) : "v"(a), "v"(b));
    return d;
}
static __device__ __forceinline__ h2v bcast2(float w) {
    const _Float16 h = (_Float16)w;
    h2v r; r.x = h; r.y = h; return r;
}

// ---------------------------------------------------------------------------
// prep: coalesced read of x chunk -> LDS; coalesced transposed write to xT;
// per-column partial sum/sumsq (no atomics). 32 blocks x 256 rows. (R6 verbatim)
// ---------------------------------------------------------------------------
__global__ __launch_bounds__(256) void prep_kernel(
    const float* __restrict__ x,
    float* __restrict__ xT,
    float* __restrict__ part)
{
    __shared__ float xs[256 * LL];          // 25.6 KB
    const int tid = threadIdx.x;
    const int b0  = blockIdx.x * 256;

    const float* src = x + (size_t)b0 * LL;
    #pragma unroll
    for (int i = 0; i < LL; ++i)
        xs[i * 256 + tid] = src[i * 256 + tid];
    __syncthreads();

    // transposed write: lanes write consecutive b -> coalesced.
    // LDS read stride 25 dwords, gcd(25,32)=1 -> 2 lanes/bank (free).
    #pragma unroll
    for (int l = 0; l < LL; ++l)
        xT[l * BATCH + b0 + tid] = xs[tid * LL + l];

    float s = 0.f, s2 = 0.f;
    if (tid < 200) {
        const int l = tid % LL;
        const int g = tid / LL;
        #pragma unroll
        for (int r = 0; r < 32; ++r) {
            const float v = xs[(g * 32 + r) * LL + l];
            s += v;
            s2 = fmaf(v, v, s2);
        }
    }
    __syncthreads();
    if (tid < 200) { xs[tid] = s; xs[200 + tid] = s2; }
    __syncthreads();

    if (tid < 50) {
        const int c = tid;
        float t = 0.f;
        if (c < LL) {
            #pragma unroll
            for (int g = 0; g < 8; ++g) t += xs[g * LL + c];
        } else {
            #pragma unroll
            for (int g = 0; g < 8; ++g) t += xs[200 + g * LL + (c - LL)];
        }
        part[blockIdx.x * 50 + c] = t;
    }
}

// ---------------------------------------------------------------------------
// eval (R9): R6 structure (stats folded into preamble, 3 launches total) +
// asm-guaranteed packed fp16 (v_pk_fma_f16 / v_pk_max_f16). Weights staged
// once per block into LDS as broadcast (w,w) pairs. xn conversion and final
// alpha-accumulate in fp32; scale/shift fp32 in LDS; alpha/b4 via s_load.
// LDS slab per j (stride WS2=152 h2v entries):
//   [0:8) w1 [8:16) b1 [16:80) w2 [80:88) b2 [88:136) w3 [136:142) b3 [142:148) w4
// ---------------------------------------------------------------------------
__global__ __launch_bounds__(256) void eval_kernel(
    const float* __restrict__ xT,
    const float* __restrict__ W1, const float* __restrict__ b1,
    const float* __restrict__ W2, const float* __restrict__ b2,
    const float* __restrict__ W3, const float* __restrict__ b3,
    const float* __restrict__ W4, const float* __restrict__ b4,
    const float* __restrict__ alpha,
    const float* __restrict__ part,
    const float* __restrict__ gamma,
    const float* __restrict__ bn_bias,
    float* __restrict__ fp)
{
    __shared__ h2v   wl[LG * WS2];          // 760 * 4B = 3.04 KB
    __shared__ float sss[2 * LG];           // scale[5], shift[5] (fp32)
    __shared__ float tmp[2 * LG];

    const int tid = threadIdx.x;
    const int k   = blockIdx.y;
    const int g   = blockIdx.z;
    const int l0  = g * LG;
    const int kl0 = k * LL + l0;
    const int b   = (blockIdx.x * 256 + tid) * VB;

    // ---- stage weights as broadcast half2 pairs (once per block) ----
    if (tid < 40) {
        const int j = tid >> 3, e = tid & 7;
        wl[j * WS2 +      e] = bcast2(W1[(kl0 + j) * 8 + e]);
        wl[j * WS2 +  8 + e] = bcast2(b1[(kl0 + j) * 8 + e]);
        wl[j * WS2 + 80 + e] = bcast2(b2[(kl0 + j) * 8 + e]);
    }
    {   // W2: 5*64 = 320 elements
        int t = tid;
        const int j = t >> 6, e = t & 63;
        wl[j * WS2 + 16 + e] = bcast2(W2[(kl0 + j) * 64 + e]);
        t += 256;
        if (t < LG * 64) {
            const int j2 = t >> 6, e2 = t & 63;
            wl[j2 * WS2 + 16 + e2] = bcast2(W2[(kl0 + j2) * 64 + e2]);
        }
    }
    if (tid < 240) {                         // W3: 5*48
        const int j = tid / 48, e = tid % 48;
        wl[j * WS2 + 88 + e] = bcast2(W3[(kl0 + j) * 48 + e]);
    }
    if (tid < 30) {                          // b3, w4: 5*6 each
        const int j = tid / 6, e = tid % 6;
        wl[j * WS2 + 136 + e] = bcast2(b3[(kl0 + j) * 6 + e]);
        wl[j * WS2 + 142 + e] = bcast2(W4[(kl0 + j) * 6 + e]);
    }

    // ---- stats preamble: reduce prep partials for this block's columns ----
    if (tid >= 128 && tid < 128 + 2 * LG) {
        const int t2  = tid - 128;                      // 0..9
        const int col = (t2 < LG) ? (l0 + t2) : (LL + l0 + t2 - LG);
        float s = 0.f;
        #pragma unroll
        for (int i = 0; i < PREPB; ++i)
            s += part[i * 50 + col];
        tmp[t2] = s;
    }
    __syncthreads();
    if (tid < LG) {
        const float s = tmp[tid], s2 = tmp[LG + tid];
        const float inv_b = 1.f / (float)BATCH;
        const float mean  = s * inv_b;
        const float var   = fmaf(s2, inv_b, -mean * mean);
        const float scale = rsqrtf(var + BN_EPS) * gamma[l0 + tid];
        sss[tid]      = scale;
        sss[LG + tid] = fmaf(-mean, scale, bn_bias[l0 + tid]);
    }
    __syncthreads();

    // ---- compute (asm-packed fp16) ----
    h2v zero2; zero2.x = (_Float16)0.f; zero2.y = (_Float16)0.f;
    float acc[VB] = {0.f, 0.f, 0.f, 0.f};

    #pragma unroll
    for (int j = 0; j < LG; ++j) {
        const int l = l0 + j;
        const h2v* w = wl + j * WS2;

        const float scale = sss[j];
        const float shift = sss[LG + j];
        const float a     = alpha[l * KK + k];        // wave-uniform s_load
        const float b4f   = b4[kl0 + j];              // wave-uniform s_load

        const float4 xv = *(const float4*)&xT[l * BATCH + b];
        h2v xn0, xn1;
        xn0.x = (_Float16)fmaf(xv.x, scale, shift);
        xn0.y = (_Float16)fmaf(xv.y, scale, shift);
        xn1.x = (_Float16)fmaf(xv.z, scale, shift);
        xn1.y = (_Float16)fmaf(xv.w, scale, shift);

        // layer 1: 1 -> 8
        h2v h1a[8], h1b[8];
        #pragma unroll
        for (int h = 0; h < 8; ++h) {
            const h2v ww = w[h], bb = w[8 + h];
            h1a[h] = pk_max(pk_fma(xn0, ww, bb), zero2);
            h1b[h] = pk_max(pk_fma(xn1, ww, bb), zero2);
        }

        // layer 2: 8 -> 8
        h2v h2a[8], h2b[8];
        #pragma unroll
        for (int i = 0; i < 8; ++i) {
            h2v t0 = w[80 + i], t1 = t0;
            #pragma unroll
            for (int h = 0; h < 8; ++h) {
                const h2v ww = w[16 + i * 8 + h];
                t0 = pk_fma(h1a[h], ww, t0);
                t1 = pk_fma(h1b[h], ww, t1);
            }
            h2a[i] = pk_max(t0, zero2);
            h2b[i] = pk_max(t1, zero2);
        }

        // layer 3: 8 -> 6
        h2v h3a[6], h3b[6];
        #pragma unroll
        for (int jj = 0; jj < 6; ++jj) {
            h2v t0 = w[136 + jj], t1 = t0;
            #pragma unroll
            for (int i = 0; i < 8; ++i) {
                const h2v ww = w[88 + jj * 8 + i];
                t0 = pk_fma(h2a[i], ww, t0);
                t1 = pk_fma(h2b[i], ww, t1);
            }
            h3a[jj] = pk_max(t0, zero2);
            h3b[jj] = pk_max(t1, zero2);
        }

        // layer 4: 6 -> 1 (packed dot), finish in fp32
        h2v fd0 = zero2, fd1 = zero2;
        #pragma unroll
        for (int jj = 0; jj < 6; ++jj) {
            const h2v ww = w[142 + jj];
            fd0 = pk_fma(h3a[jj], ww, fd0);
            fd1 = pk_fma(h3b[jj], ww, fd1);
        }
        acc[0] = fmaf(a, b4f + (float)fd0.x, acc[0]);
        acc[1] = fmaf(a, b4f + (float)fd0.y, acc[1]);
        acc[2] = fmaf(a, b4f + (float)fd1.x, acc[2]);
        acc[3] = fmaf(a, b4f + (float)fd1.y, acc[3]);
    }

    float4 o = {acc[0], acc[1], acc[2], acc[3]};
    *(float4*)&fp[(g * KK + k) * BATCH + b] = o;
}

// ---------------------------------------------------------------------------
// reduce: out[b][k] = beta[k] + sum_g fp[g][k][b]; coalesced loads. (R6 verbatim)
// ---------------------------------------------------------------------------
__global__ __launch_bounds__(256) void reduce_kernel(
    const float* __restrict__ fp,
    const float* __restrict__ beta,
    float* __restrict__ out)
{
    const int tid = threadIdx.x;
    const int k   = blockIdx.y;
    const int b   = blockIdx.x * 256 + tid;

    float acc = beta[k];
    #pragma unroll
    for (int g = 0; g < NLG; ++g)
        acc += fp[(g * KK + k) * BATCH + b];
    out[(size_t)b * KK + k] = acc;
}

// ---------------------------------------------------------------------------
// fallbacks (small workspace) — fp32, proven correct.
// ---------------------------------------------------------------------------
__device__ __forceinline__ float mlp_eval(
    float xn, int kl,
    const float* __restrict__ W1, const float* __restrict__ b1,
    const float* __restrict__ W2, const float* __restrict__ b2,
    const float* __restrict__ W3, const float* __restrict__ b3,
    const float* __restrict__ W4, const float* __restrict__ b4)
{
    const float* w1  = W1 + kl * 8;
    const float* bb1 = b1 + kl * 8;
    float h1[8];
    #pragma unroll
    for (int h = 0; h < 8; ++h)
        h1[h] = fmaxf(fmaf(xn, w1[h], bb1[h]), 0.f);

    const float* w2  = W2 + kl * 64;
    const float* bb2 = b2 + kl * 8;
    float h2v_[8];
    #pragma unroll
    for (int i = 0; i < 8; ++i) {
        float t = bb2[i];
        #pragma unroll
        for (int h = 0; h < 8; ++h)
            t = fmaf(h1[h], w2[i * 8 + h], t);
        h2v_[i] = fmaxf(t, 0.f);
    }

    const float* w3  = W3 + kl * 48;
    const float* bb3 = b3 + kl * 6;
    float h3[6];
    #pragma unroll
    for (int j = 0; j < 6; ++j) {
        float t = bb3[j];
        #pragma unroll
        for (int i = 0; i < 8; ++i)
            t = fmaf(h2v_[i], w3[j * 8 + i], t);
        h3[j] = fmaxf(t, 0.f);
    }

    const float* w4 = W4 + kl * 6;
    float f = b4[kl];
    #pragma unroll
    for (int j = 0; j < 6; ++j)
        f = fmaf(h3[j], w4[j], f);
    return f;
}

__global__ __launch_bounds__(256) void stats_small_kernel(
    const float* __restrict__ x,
    const float* __restrict__ gamma,
    const float* __restrict__ bn_bias,
    float* __restrict__ ws)
{
    const int l   = blockIdx.x;
    const int tid = threadIdx.x;

    float s = 0.f, s2 = 0.f;
    for (int b = tid; b < BATCH; b += 256) {
        float v = x[b * LL + l];
        s  += v;
        s2  = fmaf(v, v, s2);
    }
    for (int off = 32; off > 0; off >>= 1) {
        s  += __shfl_down(s,  off);
        s2 += __shfl_down(s2, off);
    }
    __shared__ float red[8];
    const int wave = tid >> 6;
    if ((tid & 63) == 0) { red[wave] = s; red[4 + wave] = s2; }
    __syncthreads();
    if (tid == 0) {
        s  = red[0] + red[1] + red[2] + red[3];
        s2 = red[4] + red[5] + red[6] + red[7];
        const float inv_b = 1.f / (float)BATCH;
        float mean = s * inv_b;
        float var  = fmaf(s2, inv_b, -mean * mean);
        float scale = rsqrtf(var + BN_EPS) * gamma[l];
        ws[WS_SCALE + l] = scale;
        ws[WS_SHIFT + l] = fmaf(-mean, scale, bn_bias[l]);
    }
}

__global__ __launch_bounds__(256) void mlp_lds_direct_kernel(
    const float* __restrict__ x,
    const float* __restrict__ W1, const float* __restrict__ b1,
    const float* __restrict__ W2, const float* __restrict__ b2,
    const float* __restrict__ W3, const float* __restrict__ b3,
    const float* __restrict__ W4, const float* __restrict__ b4,
    const float* __restrict__ alpha, const float* __restrict__ beta,
    const float* __restrict__ ws,
    float* __restrict__ out)
{
    __shared__ float xs[256 * LL];
    const int tid = threadIdx.x;
    const int k   = blockIdx.y;
    const int b0  = blockIdx.x * 256;

    const float* xsrc = x + (size_t)b0 * LL;
    #pragma unroll
    for (int i = 0; i < LL; ++i)
        xs[i * 256 + tid] = xsrc[i * 256 + tid];
    __syncthreads();

    float acc = beta[k];
    for (int l = 0; l < LL; ++l) {
        const int kl = k * LL + l;
        const float xn = fmaf(xs[tid * LL + l], ws[WS_SCALE + l], ws[WS_SHIFT + l]);
        const float f  = mlp_eval(xn, kl, W1, b1, W2, b2, W3, b3, W4, b4);
        acc = fmaf(alpha[l * KK + k], f, acc);
    }
    out[(size_t)(b0 + tid) * KK + k] = acc;
}

extern "C" void kernel_launch(void* const* d_in, const int* in_sizes, int n_in,
                              void* d_out, int out_size, void* d_ws, size_t ws_size,
                              hipStream_t stream) {
    const float* x       = (const float*)d_in[0];
    const float* gamma   = (const float*)d_in[1];
    const float* bn_bias = (const float*)d_in[2];
    const float* W1      = (const float*)d_in[3];
    const float* b1      = (const float*)d_in[4];
    const float* W2      = (const float*)d_in[5];
    const float* b2      = (const float*)d_in[6];
    const float* W3      = (const float*)d_in[7];
    const float* b3      = (const float*)d_in[8];
    const float* W4      = (const float*)d_in[9];
    const float* b4      = (const float*)d_in[10];
    const float* alpha   = (const float*)d_in[11];
    const float* beta    = (const float*)d_in[12];

    float* out = (float*)d_out;
    float* ws  = (float*)d_ws;
    float* xT  = ws + WS_XT;
    float* fp  = ws + WS_FP;

    const bool fast = ws_size >= (size_t)WS_END * sizeof(float);

    if (fast) {
        prep_kernel<<<dim3(PREPB), dim3(256), 0, stream>>>(x, xT, ws + WS_PART);
        eval_kernel<<<dim3(BATCH / (256 * VB), KK, NLG), dim3(256), 0, stream>>>(
            xT, W1, b1, W2, b2, W3, b3, W4, b4, alpha,
            ws + WS_PART, gamma, bn_bias, fp);
        reduce_kernel<<<dim3(BATCH / 256, KK), dim3(256), 0, stream>>>(fp, beta, out);
    } else {
        stats_small_kernel<<<dim3(LL), dim3(256), 0, stream>>>(x, gamma, bn_bias, ws);
        mlp_lds_direct_kernel<<<dim3(BATCH / 256, KK), dim3(256), 0, stream>>>(
            x, W1, b1, W2, b2, W3, b3, W4, b4, alpha, beta, ws, out);
    }
}

// Round 10
// 100.858 us; speedup vs baseline: 1.0357x; 1.0132x over previous
//
#include <hip/hip_runtime.h>

// Problem constants (match reference)
#define BATCH  8192
#define KK     25
#define LL     25
#define BN_EPS 1e-5f
#define PREPB  32              // prep blocks (256 rows each) — R6 proven
#define LG     5               // l-values per eval block
#define NLG    (LL / LG)
#define VB     4               // batch elements per thread in eval
#define WSP    80              // per-l LDS packed-weight slab stride (dwords)

// Workspace layout (float offsets):
#define WS_PART   0                         // [PREPB][50] partial sums
#define WS_SCALE  1600                      // (fallback path only)
#define WS_SHIFT  1632
#define WS_XT     2048                      // [LL][BATCH] transposed x
#define WS_FP     (WS_XT + LL * BATCH)      // [NLG][KK][BATCH] partial outputs
#define WS_END    (WS_FP + NLG * KK * BATCH)

// Packed fp16 pair in one VGPR. R10: weights stored as (w[2p], w[2p+1]) —
// two DIFFERENT weights per dword — and broadcast into both batch lanes via
// VOP3P op_sel modifiers. This halves the wave-uniform ds_read stream that
// R9's delta=0 identified as the eval bottleneck (LDS pipe, ~5.8cyc/read).
typedef _Float16 h2v __attribute__((ext_vector_type(2)));

// d.lane = fma(a.lane, w.lo, c.lane)
static __device__ __forceinline__ h2v pk_fma_wl(h2v a, h2v w, h2v c) {
    h2v d;
    asm("v_pk_fma_f16 %0, %1, %2, %3 op_sel:[0,0,0] op_sel_hi:[1,0,1]"
        : "=v"(d) : "v"(a), "v"(w), "v"(c));
    return d;
}
// d.lane = fma(a.lane, w.hi, c.lane)
static __device__ __forceinline__ h2v pk_fma_wh(h2v a, h2v w, h2v c) {
    h2v d;
    asm("v_pk_fma_f16 %0, %1, %2, %3 op_sel:[0,1,0] op_sel_hi:[1,1,1]"
        : "=v"(d) : "v"(a), "v"(w), "v"(c));
    return d;
}
// d.lane = fma(a.lane, w.lo, c.lo)
static __device__ __forceinline__ h2v pk_fma_wl_cl(h2v a, h2v w, h2v c) {
    h2v d;
    asm("v_pk_fma_f16 %0, %1, %2, %3 op_sel:[0,0,0] op_sel_hi:[1,0,0]"
        : "=v"(d) : "v"(a), "v"(w), "v"(c));
    return d;
}
// d.lane = fma(a.lane, w.lo, c.hi)
static __device__ __forceinline__ h2v pk_fma_wl_ch(h2v a, h2v w, h2v c) {
    h2v d;
    asm("v_pk_fma_f16 %0, %1, %2, %3 op_sel:[0,0,1] op_sel_hi:[1,0,1]"
        : "=v"(d) : "v"(a), "v"(w), "v"(c));
    return d;
}
// d.lane = fma(a.lane, w.hi, c.hi)
static __device__ __forceinline__ h2v pk_fma_wh_ch(h2v a, h2v w, h2v c) {
    h2v d;
    asm("v_pk_fma_f16 %0, %1, %2, %3 op_sel:[0,1,1] op_sel_hi:[1,1,1]"
        : "=v"(d) : "v"(a), "v"(w), "v"(c));
    return d;
}
static __device__ __forceinline__ h2v pk_max(h2v a, h2v b) {
    h2v d;
    asm("v_pk_max_f16 %0, %1, %2" : "=v"(d) : "v"(a), "v"(b));
    return d;
}
static __device__ __forceinline__ h2v pack2(float a, float b) {
    h2v r; r.x = (_Float16)a; r.y = (_Float16)b; return r;
}

// ---------------------------------------------------------------------------
// prep: coalesced read of x chunk -> LDS; coalesced transposed write to xT;
// per-column partial sum/sumsq (no atomics). 32 blocks x 256 rows. (R6 verbatim)
// ---------------------------------------------------------------------------
__global__ __launch_bounds__(256) void prep_kernel(
    const float* __restrict__ x,
    float* __restrict__ xT,
    float* __restrict__ part)
{
    __shared__ float xs[256 * LL];          // 25.6 KB
    const int tid = threadIdx.x;
    const int b0  = blockIdx.x * 256;

    const float* src = x + (size_t)b0 * LL;
    #pragma unroll
    for (int i = 0; i < LL; ++i)
        xs[i * 256 + tid] = src[i * 256 + tid];
    __syncthreads();

    #pragma unroll
    for (int l = 0; l < LL; ++l)
        xT[l * BATCH + b0 + tid] = xs[tid * LL + l];

    float s = 0.f, s2 = 0.f;
    if (tid < 200) {
        const int l = tid % LL;
        const int g = tid / LL;
        #pragma unroll
        for (int r = 0; r < 32; ++r) {
            const float v = xs[(g * 32 + r) * LL + l];
            s += v;
            s2 = fmaf(v, v, s2);
        }
    }
    __syncthreads();
    if (tid < 200) { xs[tid] = s; xs[200 + tid] = s2; }
    __syncthreads();

    if (tid < 50) {
        const int c = tid;
        float t = 0.f;
        if (c < LL) {
            #pragma unroll
            for (int g = 0; g < 8; ++g) t += xs[g * LL + c];
        } else {
            #pragma unroll
            for (int g = 0; g < 8; ++g) t += xs[200 + g * LL + (c - LL)];
        }
        part[blockIdx.x * 50 + c] = t;
    }
}

// ---------------------------------------------------------------------------
// eval (R10): R9 structure; LDS weight slab now stores PACKED PAIRS of
// distinct weights (one dword = two weights), broadcast per-half via op_sel.
// ds_read dword stream per l-iter: 148 -> 74 (the R9-identified bottleneck).
// LDS slab per j (stride WSP=80 dwords):
//   [0:4) w1p [4:8) b1p [8:40) w2p [40:44) b2p [44:68) w3p [68:71) b3p [71:74) w4p
//   pair p of array A holds (A[2p], A[2p+1]).
// ---------------------------------------------------------------------------
__global__ __launch_bounds__(256) void eval_kernel(
    const float* __restrict__ xT,
    const float* __restrict__ W1, const float* __restrict__ b1,
    const float* __restrict__ W2, const float* __restrict__ b2,
    const float* __restrict__ W3, const float* __restrict__ b3,
    const float* __restrict__ W4, const float* __restrict__ b4,
    const float* __restrict__ alpha,
    const float* __restrict__ part,
    const float* __restrict__ gamma,
    const float* __restrict__ bn_bias,
    float* __restrict__ fp)
{
    __shared__ h2v   wl[LG * WSP];          // 400 dwords = 1.6 KB
    __shared__ float sss[2 * LG];           // scale[5], shift[5] (fp32)
    __shared__ float tmp[2 * LG];

    const int tid = threadIdx.x;
    const int k   = blockIdx.y;
    const int g   = blockIdx.z;
    const int l0  = g * LG;
    const int kl0 = k * LL + l0;
    const int b   = (blockIdx.x * 256 + tid) * VB;

    // ---- stage weights as packed pairs (once per block) ----
    if (tid < 160) {                         // w2p: 5*32
        const int j = tid >> 5, p = tid & 31;
        const float* s = W2 + (kl0 + j) * 64 + 2 * p;
        wl[j * WSP + 8 + p] = pack2(s[0], s[1]);
    }
    if (tid < 120) {                         // w3p: 5*24
        const int j = tid / 24, p = tid % 24;
        const float* s = W3 + (kl0 + j) * 48 + 2 * p;
        wl[j * WSP + 44 + p] = pack2(s[0], s[1]);
    }
    if (tid < 20) {                          // w1p, b1p, b2p: 5*4 each
        const int j = tid >> 2, p = tid & 3;
        const float* s1 = W1 + (kl0 + j) * 8 + 2 * p;
        const float* t1 = b1 + (kl0 + j) * 8 + 2 * p;
        const float* t2 = b2 + (kl0 + j) * 8 + 2 * p;
        wl[j * WSP +      p] = pack2(s1[0], s1[1]);
        wl[j * WSP +  4 + p] = pack2(t1[0], t1[1]);
        wl[j * WSP + 40 + p] = pack2(t2[0], t2[1]);
    }
    if (tid < 15) {                          // b3p, w4p: 5*3 each
        const int j = tid / 3, p = tid % 3;
        const float* t3 = b3 + (kl0 + j) * 6 + 2 * p;
        const float* s4 = W4 + (kl0 + j) * 6 + 2 * p;
        wl[j * WSP + 68 + p] = pack2(t3[0], t3[1]);
        wl[j * WSP + 71 + p] = pack2(s4[0], s4[1]);
    }

    // ---- stats preamble: reduce prep partials for this block's columns ----
    if (tid >= 128 && tid < 128 + 2 * LG) {
        const int t2  = tid - 128;                      // 0..9
        const int col = (t2 < LG) ? (l0 + t2) : (LL + l0 + t2 - LG);
        float s = 0.f;
        #pragma unroll
        for (int i = 0; i < PREPB; ++i)
            s += part[i * 50 + col];
        tmp[t2] = s;
    }
    __syncthreads();
    if (tid < LG) {
        const float s = tmp[tid], s2 = tmp[LG + tid];
        const float inv_b = 1.f / (float)BATCH;
        const float mean  = s * inv_b;
        const float var   = fmaf(s2, inv_b, -mean * mean);
        const float scale = rsqrtf(var + BN_EPS) * gamma[l0 + tid];
        sss[tid]      = scale;
        sss[LG + tid] = fmaf(-mean, scale, bn_bias[l0 + tid]);
    }
    __syncthreads();

    // ---- compute (packed fp16, op_sel weight broadcast) ----
    h2v zero2; zero2.x = (_Float16)0.f; zero2.y = (_Float16)0.f;
    float acc[VB] = {0.f, 0.f, 0.f, 0.f};

    #pragma unroll
    for (int j = 0; j < LG; ++j) {
        const int l = l0 + j;
        const h2v* w = wl + j * WSP;

        const float scale = sss[j];
        const float shift = sss[LG + j];
        const float a     = alpha[l * KK + k];        // wave-uniform s_load
        const float b4f   = b4[kl0 + j];              // wave-uniform s_load

        const float4 xv = *(const float4*)&xT[l * BATCH + b];
        h2v xn0, xn1;
        xn0.x = (_Float16)fmaf(xv.x, scale, shift);
        xn0.y = (_Float16)fmaf(xv.y, scale, shift);
        xn1.x = (_Float16)fmaf(xv.z, scale, shift);
        xn1.y = (_Float16)fmaf(xv.w, scale, shift);

        // layer 1: 1 -> 8  (w1p[p]=(w1[2p],w1[2p+1]), b1p same)
        h2v h1a[8], h1b[8];
        #pragma unroll
        for (int p = 0; p < 4; ++p) {
            const h2v wp = w[p], bp = w[4 + p];
            h1a[2*p]   = pk_max(pk_fma_wl_cl(xn0, wp, bp), zero2);
            h1a[2*p+1] = pk_max(pk_fma_wh_ch(xn0, wp, bp), zero2);
            h1b[2*p]   = pk_max(pk_fma_wl_cl(xn1, wp, bp), zero2);
            h1b[2*p+1] = pk_max(pk_fma_wh_ch(xn1, wp, bp), zero2);
        }

        // layer 2: 8 -> 8  (w2p[i*4+hp]=(w2[i*8+2hp], w2[i*8+2hp+1]))
        h2v h2a[8], h2b[8];
        #pragma unroll
        for (int i = 0; i < 8; ++i) {
            const h2v bp = w[40 + (i >> 1)];
            const h2v w0 = w[8 + i * 4];
            h2v t0, t1;
            if (i & 1) { t0 = pk_fma_wl_ch(h1a[0], w0, bp);
                         t1 = pk_fma_wl_ch(h1b[0], w0, bp); }
            else       { t0 = pk_fma_wl_cl(h1a[0], w0, bp);
                         t1 = pk_fma_wl_cl(h1b[0], w0, bp); }
            t0 = pk_fma_wh(h1a[1], w0, t0);
            t1 = pk_fma_wh(h1b[1], w0, t1);
            #pragma unroll
            for (int hp = 1; hp < 4; ++hp) {
                const h2v wp = w[8 + i * 4 + hp];
                t0 = pk_fma_wl(h1a[2*hp],   wp, t0);
                t1 = pk_fma_wl(h1b[2*hp],   wp, t1);
                t0 = pk_fma_wh(h1a[2*hp+1], wp, t0);
                t1 = pk_fma_wh(h1b[2*hp+1], wp, t1);
            }
            h2a[i] = pk_max(t0, zero2);
            h2b[i] = pk_max(t1, zero2);
        }

        // layer 3: 8 -> 6  (w3p[jj*4+ip])
        h2v h3a[6], h3b[6];
        #pragma unroll
        for (int jj = 0; jj < 6; ++jj) {
            const h2v bp = w[68 + (jj >> 1)];
            const h2v w0 = w[44 + jj * 4];
            h2v t0, t1;
            if (jj & 1) { t0 = pk_fma_wl_ch(h2a[0], w0, bp);
                          t1 = pk_fma_wl_ch(h2b[0], w0, bp); }
            else        { t0 = pk_fma_wl_cl(h2a[0], w0, bp);
                          t1 = pk_fma_wl_cl(h2b[0], w0, bp); }
            t0 = pk_fma_wh(h2a[1], w0, t0);
            t1 = pk_fma_wh(h2b[1], w0, t1);
            #pragma unroll
            for (int ip = 1; ip < 4; ++ip) {
                const h2v wp = w[44 + jj * 4 + ip];
                t0 = pk_fma_wl(h2a[2*ip],   wp, t0);
                t1 = pk_fma_wl(h2b[2*ip],   wp, t1);
                t0 = pk_fma_wh(h2a[2*ip+1], wp, t0);
                t1 = pk_fma_wh(h2b[2*ip+1], wp, t1);
            }
            h3a[jj] = pk_max(t0, zero2);
            h3b[jj] = pk_max(t1, zero2);
        }

        // layer 4: 6 -> 1 (w4p[jp]=(w4[2jp],w4[2jp+1])), finish in fp32
        h2v fd0 = zero2, fd1 = zero2;
        #pragma unroll
        for (int jp = 0; jp < 3; ++jp) {
            const h2v wp = w[71 + jp];
            fd0 = pk_fma_wl(h3a[2*jp],   wp, fd0);
            fd1 = pk_fma_wl(h3b[2*jp],   wp, fd1);
            fd0 = pk_fma_wh(h3a[2*jp+1], wp, fd0);
            fd1 = pk_fma_wh(h3b[2*jp+1], wp, fd1);
        }
        acc[0] = fmaf(a, b4f + (float)fd0.x, acc[0]);
        acc[1] = fmaf(a, b4f + (float)fd0.y, acc[1]);
        acc[2] = fmaf(a, b4f + (float)fd1.x, acc[2]);
        acc[3] = fmaf(a, b4f + (float)fd1.y, acc[3]);
    }

    float4 o = {acc[0], acc[1], acc[2], acc[3]};
    *(float4*)&fp[(g * KK + k) * BATCH + b] = o;
}

// ---------------------------------------------------------------------------
// reduce: out[b][k] = beta[k] + sum_g fp[g][k][b]; coalesced loads. (R6 verbatim)
// ---------------------------------------------------------------------------
__global__ __launch_bounds__(256) void reduce_kernel(
    const float* __restrict__ fp,
    const float* __restrict__ beta,
    float* __restrict__ out)
{
    const int tid = threadIdx.x;
    const int k   = blockIdx.y;
    const int b   = blockIdx.x * 256 + tid;

    float acc = beta[k];
    #pragma unroll
    for (int g = 0; g < NLG; ++g)
        acc += fp[(g * KK + k) * BATCH + b];
    out[(size_t)b * KK + k] = acc;
}

// ---------------------------------------------------------------------------
// fallbacks (small workspace) — fp32, proven correct.
// ---------------------------------------------------------------------------
__device__ __forceinline__ float mlp_eval(
    float xn, int kl,
    const float* __restrict__ W1, const float* __restrict__ b1,
    const float* __restrict__ W2, const float* __restrict__ b2,
    const float* __restrict__ W3, const float* __restrict__ b3,
    const float* __restrict__ W4, const float* __restrict__ b4)
{
    const float* w1  = W1 + kl * 8;
    const float* bb1 = b1 + kl * 8;
    float h1[8];
    #pragma unroll
    for (int h = 0; h < 8; ++h)
        h1[h] = fmaxf(fmaf(xn, w1[h], bb1[h]), 0.f);

    const float* w2  = W2 + kl * 64;
    const float* bb2 = b2 + kl * 8;
    float h2v_[8];
    #pragma unroll
    for (int i = 0; i < 8; ++i) {
        float t = bb2[i];
        #pragma unroll
        for (int h = 0; h < 8; ++h)
            t = fmaf(h1[h], w2[i * 8 + h], t);
        h2v_[i] = fmaxf(t, 0.f);
    }

    const float* w3  = W3 + kl * 48;
    const float* bb3 = b3 + kl * 6;
    float h3[6];
    #pragma unroll
    for (int j = 0; j < 6; ++j) {
        float t = bb3[j];
        #pragma unroll
        for (int i = 0; i < 8; ++i)
            t = fmaf(h2v_[i], w3[j * 8 + i], t);
        h3[j] = fmaxf(t, 0.f);
    }

    const float* w4 = W4 + kl * 6;
    float f = b4[kl];
    #pragma unroll
    for (int j = 0; j < 6; ++j)
        f = fmaf(h3[j], w4[j], f);
    return f;
}

__global__ __launch_bounds__(256) void stats_small_kernel(
    const float* __restrict__ x,
    const float* __restrict__ gamma,
    const float* __restrict__ bn_bias,
    float* __restrict__ ws)
{
    const int l   = blockIdx.x;
    const int tid = threadIdx.x;

    float s = 0.f, s2 = 0.f;
    for (int b = tid; b < BATCH; b += 256) {
        float v = x[b * LL + l];
        s  += v;
        s2  = fmaf(v, v, s2);
    }
    for (int off = 32; off > 0; off >>= 1) {
        s  += __shfl_down(s,  off);
        s2 += __shfl_down(s2, off);
    }
    __shared__ float red[8];
    const int wave = tid >> 6;
    if ((tid & 63) == 0) { red[wave] = s; red[4 + wave] = s2; }
    __syncthreads();
    if (tid == 0) {
        s  = red[0] + red[1] + red[2] + red[3];
        s2 = red[4] + red[5] + red[6] + red[7];
        const float inv_b = 1.f / (float)BATCH;
        float mean = s * inv_b;
        float var  = fmaf(s2, inv_b, -mean * mean);
        float scale = rsqrtf(var + BN_EPS) * gamma[l];
        ws[WS_SCALE + l] = scale;
        ws[WS_SHIFT + l] = fmaf(-mean, scale, bn_bias[l]);
    }
}

__global__ __launch_bounds__(256) void mlp_lds_direct_kernel(
    const float* __restrict__ x,
    const float* __restrict__ W1, const float* __restrict__ b1,
    const float* __restrict__ W2, const float* __restrict__ b2,
    const float* __restrict__ W3, const float* __restrict__ b3,
    const float* __restrict__ W4, const float* __restrict__ b4,
    const float* __restrict__ alpha, const float* __restrict__ beta,
    const float* __restrict__ ws,
    float* __restrict__ out)
{
    __shared__ float xs[256 * LL];
    const int tid = threadIdx.x;
    const int k   = blockIdx.y;
    const int b0  = blockIdx.x * 256;

    const float* xsrc = x + (size_t)b0 * LL;
    #pragma unroll
    for (int i = 0; i < LL; ++i)
        xs[i * 256 + tid] = xsrc[i * 256 + tid];
    __syncthreads();

    float acc = beta[k];
    for (int l = 0; l < LL; ++l) {
        const int kl = k * LL + l;
        const float xn = fmaf(xs[tid * LL + l], ws[WS_SCALE + l], ws[WS_SHIFT + l]);
        const float f  = mlp_eval(xn, kl, W1, b1, W2, b2, W3, b3, W4, b4);
        acc = fmaf(alpha[l * KK + k], f, acc);
    }
    out[(size_t)(b0 + tid) * KK + k] = acc;
}

extern "C" void kernel_launch(void* const* d_in, const int* in_sizes, int n_in,
                              void* d_out, int out_size, void* d_ws, size_t ws_size,
                              hipStream_t stream) {
    const float* x       = (const float*)d_in[0];
    const float* gamma   = (const float*)d_in[1];
    const float* bn_bias = (const float*)d_in[2];
    const float* W1      = (const float*)d_in[3];
    const float* b1      = (const float*)d_in[4];
    const float* W2      = (const float*)d_in[5];
    const float* b2      = (const float*)d_in[6];
    const float* W3      = (const float*)d_in[7];
    const float* b3      = (const float*)d_in[8];
    const float* W4      = (const float*)d_in[9];
    const float* b4      = (const float*)d_in[10];
    const float* alpha   = (const float*)d_in[11];
    const float* beta    = (const float*)d_in[12];

    float* out = (float*)d_out;
    float* ws  = (float*)d_ws;
    float* xT  = ws + WS_XT;
    float* fp  = ws + WS_FP;

    const bool fast = ws_size >= (size_t)WS_END * sizeof(float);

    if (fast) {
        prep_kernel<<<dim3(PREPB), dim3(256), 0, stream>>>(x, xT, ws + WS_PART);
        eval_kernel<<<dim3(BATCH / (256 * VB), KK, NLG), dim3(256), 0, stream>>>(
            xT, W1, b1, W2, b2, W3, b3, W4, b4, alpha,
            ws + WS_PART, gamma, bn_bias, fp);
        reduce_kernel<<<dim3(BATCH / 256, KK), dim3(256), 0, stream>>>(fp, beta, out);
    } else {
        stats_small_kernel<<<dim3(LL), dim3(256), 0, stream>>>(x, gamma, bn_bias, ws);
        mlp_lds_direct_kernel<<<dim3(BATCH / 256, KK), dim3(256), 0, stream>>>(
            x, W1, b1, W2, b2, W3, b3, W4, b4, alpha, beta, ws, out);
    }
}